// Round 1
// baseline (697.933 us; speedup 1.0000x reference)
//
#include <hip/hip_runtime.h>
#include <hip/hip_bf16.h>

// Problem constants
#define SEQ   2048
#define BATCH 4
#define DM    768
#define NH    12
#define HD    64
#define MTOT  (BATCH*SEQ)   // 8192

typedef short bf16x8 __attribute__((ext_vector_type(8)));   // 8 bf16 = 4 VGPRs (guide §3)
typedef float f32x4  __attribute__((ext_vector_type(4)));

static __device__ __forceinline__ short f2bf(float f) {
  union { __hip_bfloat16 h; short s; } u;
  u.h = __float2bfloat16(f);
  return u.s;
}

// ---------------------------------------------------------------- fp32 -> bf16
__global__ void cvt_kernel(const float* __restrict__ in, short* __restrict__ out, int n4) {
  int i = blockIdx.x * blockDim.x + threadIdx.x;
  if (i >= n4) return;
  float4 v = reinterpret_cast<const float4*>(in)[i];
  short4 o;
  o.x = f2bf(v.x); o.y = f2bf(v.y); o.z = f2bf(v.z); o.w = f2bf(v.w);
  reinterpret_cast<short4*>(out)[i] = o;
}

// ------------------------------------------------- shared 32x32-per-wave GEMM core
// C[m][n] = sum_k A[m][k] * W[n][k]   (A, W row-major, K contiguous -> B^T GEMM)
static __device__ __forceinline__ void gemm_tile(
    const short* __restrict__ A, const short* __restrict__ W,
    int m0, int n0, int lq, int quad, f32x4 acc[2][2])
{
  const short* a0p = A + (size_t)(m0 + lq) * DM + quad * 8;
  const short* a1p = a0p + 16 * DM;
  const short* b0p = W + (size_t)(n0 + lq) * DM + quad * 8;
  const short* b1p = b0p + 16 * DM;
#pragma unroll 4
  for (int k0 = 0; k0 < DM; k0 += 32) {
    bf16x8 a0 = *(const bf16x8*)(a0p + k0);
    bf16x8 a1 = *(const bf16x8*)(a1p + k0);
    bf16x8 b0 = *(const bf16x8*)(b0p + k0);
    bf16x8 b1 = *(const bf16x8*)(b1p + k0);
    acc[0][0] = __builtin_amdgcn_mfma_f32_16x16x32_bf16(a0, b0, acc[0][0], 0, 0, 0);
    acc[0][1] = __builtin_amdgcn_mfma_f32_16x16x32_bf16(a0, b1, acc[0][1], 0, 0, 0);
    acc[1][0] = __builtin_amdgcn_mfma_f32_16x16x32_bf16(a1, b0, acc[1][0], 0, 0, 0);
    acc[1][1] = __builtin_amdgcn_mfma_f32_16x16x32_bf16(a1, b1, acc[1][1], 0, 0, 0);
  }
}

// --------------------------------------------------------------- QKV projection
// grid (12, 128, 3), block 256. z selects Q/K/V weight & destination layout.
__global__ __launch_bounds__(256) void qkv_gemm(
    const short* __restrict__ xb, const short* __restrict__ Wqb,
    const short* __restrict__ Wkb, const short* __restrict__ Wvb,
    short* __restrict__ Qb, short* __restrict__ Kb, short* __restrict__ VTb)
{
  const int z = blockIdx.z;
  const short* W = (z == 0) ? Wqb : (z == 1) ? Wkb : Wvb;
  const int lane = threadIdx.x & 63;
  const int wv = threadIdx.x >> 6;
  const int quad = lane >> 4, lq = lane & 15;
  const int m0 = blockIdx.y * 64 + (wv & 1) * 32;
  const int n0 = blockIdx.x * 64 + (wv >> 1) * 32;
  f32x4 acc[2][2] = {};
  gemm_tile(xb, W, m0, n0, lq, quad, acc);
#pragma unroll
  for (int mt = 0; mt < 2; ++mt)
#pragma unroll
    for (int nt = 0; nt < 2; ++nt)
#pragma unroll
      for (int r = 0; r < 4; ++r) {
        const int m = m0 + mt * 16 + quad * 4 + r;       // C/D: row = quad*4+reg
        const int n = n0 + nt * 16 + lq;                 // C/D: col = lane&15
        const int b = m >> 11, s = m & 2047;
        const int h = n >> 6, d = n & 63;
        const short v = f2bf(acc[mt][nt][r]);
        if (z == 0)      Qb[((size_t)(b * NH + h) * SEQ + s) * HD + d] = v;
        else if (z == 1) Kb[((size_t)(b * NH + h) * SEQ + s) * HD + d] = v;
        else             VTb[((size_t)(b * NH + h) * HD + d) * SEQ + s] = v; // V^T for PV B-frag
      }
}

// ------------------------------------------------------------ flash attention
// grid (SEQ/64, BATCH*NH), block 256 = 4 waves; each wave owns 16 queries,
// fully independent (private LDS P buffer, no __syncthreads).
__global__ __launch_bounds__(256) void attn_kernel(
    const short* __restrict__ Qb, const short* __restrict__ Kb,
    const short* __restrict__ VTb, short* __restrict__ AOb)
{
  __shared__ __align__(16) short Plds[4][16][32];
  const int bh = blockIdx.y;
  const int b = bh / NH, h = bh % NH;
  const int w = threadIdx.x >> 6;
  const int lane = threadIdx.x & 63;
  const int quad = lane >> 4, lq = lane & 15;
  const int qbase = blockIdx.x * 64 + w * 16;

  const short* Qh = Qb  + (size_t)bh * SEQ * HD;
  const short* Kh = Kb  + (size_t)bh * SEQ * HD;
  const short* Vh = VTb + (size_t)bh * HD * SEQ;

  const bf16x8 aq0 = *(const bf16x8*)(Qh + (qbase + lq) * HD + quad * 8);
  const bf16x8 aq1 = *(const bf16x8*)(Qh + (qbase + lq) * HD + 32 + quad * 8);

  f32x4 o0 = {0,0,0,0}, o1 = {0,0,0,0}, o2 = {0,0,0,0}, o3 = {0,0,0,0};
  float m_i[4], l_i[4];
#pragma unroll
  for (int r = 0; r < 4; ++r) { m_i[r] = -3e38f; l_i[r] = 0.0f; }
  const float scale = 0.125f;   // 1/sqrt(64)
  const int rq = qbase + quad * 4;

  for (int kb = 0; kb < qbase + 16; kb += 32) {
    const short* Krow = Kh + (size_t)(kb + lq) * HD + quad * 8;
    bf16x8 bk0a = *(const bf16x8*)(Krow);
    bf16x8 bk0b = *(const bf16x8*)(Krow + 32);
    bf16x8 bk1a = *(const bf16x8*)(Krow + 16 * HD);
    bf16x8 bk1b = *(const bf16x8*)(Krow + 16 * HD + 32);
    f32x4 s0 = {0,0,0,0}, s1 = {0,0,0,0};
    s0 = __builtin_amdgcn_mfma_f32_16x16x32_bf16(aq0, bk0a, s0, 0, 0, 0);
    s0 = __builtin_amdgcn_mfma_f32_16x16x32_bf16(aq1, bk0b, s0, 0, 0, 0);
    s1 = __builtin_amdgcn_mfma_f32_16x16x32_bf16(aq0, bk1a, s1, 0, 0, 0);
    s1 = __builtin_amdgcn_mfma_f32_16x16x32_bf16(aq1, bk1b, s1, 0, 0, 0);

    const int c0 = kb + lq, c1 = kb + 16 + lq;
    float v0[4], v1[4], mx[4];
#pragma unroll
    for (int r = 0; r < 4; ++r) {
      const int q = rq + r;
      v0[r] = (c0 <= q) ? s0[r] * scale : -3e38f;
      v1[r] = (c1 <= q) ? s1[r] * scale : -3e38f;
      mx[r] = fmaxf(v0[r], v1[r]);
    }
#pragma unroll
    for (int off = 1; off < 16; off <<= 1)
#pragma unroll
      for (int r = 0; r < 4; ++r)
        mx[r] = fmaxf(mx[r], __shfl_xor(mx[r], off, 16));

    float alpha[4], p0[4], p1[4], rs[4];
#pragma unroll
    for (int r = 0; r < 4; ++r) {
      const float mn = fmaxf(m_i[r], mx[r]);
      alpha[r] = __expf(m_i[r] - mn);
      m_i[r] = mn;
      p0[r] = __expf(v0[r] - mn);
      p1[r] = __expf(v1[r] - mn);
      rs[r] = p0[r] + p1[r];
    }
#pragma unroll
    for (int off = 1; off < 16; off <<= 1)
#pragma unroll
      for (int r = 0; r < 4; ++r)
        rs[r] += __shfl_xor(rs[r], off, 16);
#pragma unroll
    for (int r = 0; r < 4; ++r) {
      l_i[r] = l_i[r] * alpha[r] + rs[r];
      o0[r] *= alpha[r]; o1[r] *= alpha[r]; o2[r] *= alpha[r]; o3[r] *= alpha[r];
    }

    // P (C-layout) -> LDS -> A-layout for PV (m120-verified transform)
#pragma unroll
    for (int r = 0; r < 4; ++r) {
      Plds[w][quad * 4 + r][lq]      = f2bf(p0[r]);
      Plds[w][quad * 4 + r][16 + lq] = f2bf(p1[r]);
    }
    asm volatile("s_waitcnt lgkmcnt(0)" ::: "memory");  // within-wave LDS write->read
    const bf16x8 pa = *(const bf16x8*)(&Plds[w][lq][quad * 8]);

    const short* Vcol = Vh + (size_t)lq * SEQ + kb + quad * 8;   // V^T rows = head dims
    bf16x8 bv0 = *(const bf16x8*)(Vcol);
    bf16x8 bv1 = *(const bf16x8*)(Vcol + 16 * SEQ);
    bf16x8 bv2 = *(const bf16x8*)(Vcol + 32 * SEQ);
    bf16x8 bv3 = *(const bf16x8*)(Vcol + 48 * SEQ);
    o0 = __builtin_amdgcn_mfma_f32_16x16x32_bf16(pa, bv0, o0, 0, 0, 0);
    o1 = __builtin_amdgcn_mfma_f32_16x16x32_bf16(pa, bv1, o1, 0, 0, 0);
    o2 = __builtin_amdgcn_mfma_f32_16x16x32_bf16(pa, bv2, o2, 0, 0, 0);
    o3 = __builtin_amdgcn_mfma_f32_16x16x32_bf16(pa, bv3, o3, 0, 0, 0);
  }

#pragma unroll
  for (int r = 0; r < 4; ++r) {
    const float inv = 1.0f / l_i[r];
    const int s = qbase + quad * 4 + r;
    short* dst = AOb + ((size_t)(b * SEQ + s)) * DM + h * HD + lq;
    dst[0]  = f2bf(o0[r] * inv);
    dst[16] = f2bf(o1[r] * inv);
    dst[32] = f2bf(o2[r] * inv);
    dst[48] = f2bf(o3[r] * inv);
  }
}

// ----------------------------------------------------------- output projection
__global__ __launch_bounds__(256) void out_gemm(
    const short* __restrict__ AOb, const short* __restrict__ Wob, float* __restrict__ C)
{
  const int lane = threadIdx.x & 63;
  const int wv = threadIdx.x >> 6;
  const int quad = lane >> 4, lq = lane & 15;
  const int m0 = blockIdx.y * 64 + (wv & 1) * 32;
  const int n0 = blockIdx.x * 64 + (wv >> 1) * 32;
  f32x4 acc[2][2] = {};
  gemm_tile(AOb, Wob, m0, n0, lq, quad, acc);
#pragma unroll
  for (int mt = 0; mt < 2; ++mt)
#pragma unroll
    for (int nt = 0; nt < 2; ++nt)
#pragma unroll
      for (int r = 0; r < 4; ++r) {
        const int m = m0 + mt * 16 + quad * 4 + r;
        const int n = n0 + nt * 16 + lq;
        C[(size_t)m * DM + n] = acc[mt][nt][r];
      }
}

// ------------------------------------------------------------------- launcher
extern "C" void kernel_launch(void* const* d_in, const int* in_sizes, int n_in,
                              void* d_out, int out_size, void* d_ws, size_t ws_size,
                              hipStream_t stream) {
  const float* x  = (const float*)d_in[0];
  const float* Wq = (const float*)d_in[1];
  const float* Wk = (const float*)d_in[2];
  const float* Wv = (const float*)d_in[3];
  const float* Wo = (const float*)d_in[4];
  float* out = (float*)d_out;

  // workspace layout (bf16 shorts), ~55 MB total
  short* xb  = (short*)d_ws;                       // 8192*768
  short* Wqb = xb  + (size_t)MTOT * DM;
  short* Wkb = Wqb + DM * DM;
  short* Wvb = Wkb + DM * DM;
  short* Wob = Wvb + DM * DM;
  short* Qb  = Wob + DM * DM;                      // (b,h,s,d)
  short* Kb  = Qb  + (size_t)MTOT * DM;            // (b,h,s,d)
  short* VTb = Kb  + (size_t)MTOT * DM;            // (b,h,d,s)
  short* AOb = xb;                                 // alias: xb dead after qkv_gemm

  cvt_kernel<<<(MTOT * DM / 4 + 255) / 256, 256, 0, stream>>>(x, xb, MTOT * DM / 4);
  cvt_kernel<<<(DM * DM / 4 + 255) / 256, 256, 0, stream>>>(Wq, Wqb, DM * DM / 4);
  cvt_kernel<<<(DM * DM / 4 + 255) / 256, 256, 0, stream>>>(Wk, Wkb, DM * DM / 4);
  cvt_kernel<<<(DM * DM / 4 + 255) / 256, 256, 0, stream>>>(Wv, Wvb, DM * DM / 4);
  cvt_kernel<<<(DM * DM / 4 + 255) / 256, 256, 0, stream>>>(Wo, Wob, DM * DM / 4);

  qkv_gemm<<<dim3(DM / 64, MTOT / 64, 3), 256, 0, stream>>>(xb, Wqb, Wkb, Wvb, Qb, Kb, VTb);
  attn_kernel<<<dim3(SEQ / 64, BATCH * NH), 256, 0, stream>>>(Qb, Kb, VTb, AOb);
  out_gemm<<<dim3(DM / 64, MTOT / 64), 256, 0, stream>>>(AOb, Wob, out);
}

// Round 2
// 356.824 us; speedup vs baseline: 1.9560x; 1.9560x over previous
//
#include <hip/hip_runtime.h>
#include <hip/hip_bf16.h>

// Problem constants
#define SEQ   2048
#define BATCH 4
#define DM    768
#define NH    12
#define HD    64
#define MTOT  (BATCH*SEQ)   // 8192

typedef short bf16x8 __attribute__((ext_vector_type(8)));   // 8 bf16 = 4 VGPRs
typedef float f32x4  __attribute__((ext_vector_type(4)));

static __device__ __forceinline__ short f2bf(float f) {
  union { __hip_bfloat16 h; short s; } u;
  u.h = __float2bfloat16(f);
  return u.s;
}

// ---------------------------------------------------------------- fp32 -> bf16
__global__ void cvt_kernel(const float* __restrict__ in, short* __restrict__ out, int n4) {
  int i = blockIdx.x * blockDim.x + threadIdx.x;
  if (i >= n4) return;
  float4 v = reinterpret_cast<const float4*>(in)[i];
  short4 o;
  o.x = f2bf(v.x); o.y = f2bf(v.y); o.z = f2bf(v.z); o.w = f2bf(v.w);
  reinterpret_cast<short4*>(out)[i] = o;
}

// -------------------------------------------- 64x64-per-wave GEMM core (4x4 tiles)
// C[m][n] = sum_k A[m][k] * W[n][k]   (A, W row-major, K contiguous -> B^T GEMM)
static __device__ __forceinline__ void gemm_core_64(
    const short* __restrict__ A, const short* __restrict__ W,
    int m0, int n0, int lq, int quad, f32x4 acc[4][4])
{
  const short* ap = A + (size_t)(m0 + lq) * DM + quad * 8;
  const short* bp = W + (size_t)(n0 + lq) * DM + quad * 8;
#pragma unroll 2
  for (int k0 = 0; k0 < DM; k0 += 32) {
    bf16x8 a[4], b[4];
#pragma unroll
    for (int i = 0; i < 4; ++i) {
      a[i] = *(const bf16x8*)(ap + (size_t)i * 16 * DM + k0);
      b[i] = *(const bf16x8*)(bp + (size_t)i * 16 * DM + k0);
    }
#pragma unroll
    for (int mt = 0; mt < 4; ++mt)
#pragma unroll
      for (int nt = 0; nt < 4; ++nt)
        acc[mt][nt] = __builtin_amdgcn_mfma_f32_16x16x32_bf16(a[mt], b[nt], acc[mt][nt], 0, 0, 0);
  }
}

// --------------------------------------------------------------- QKV projection
// grid (6, 64, 3), block 256 (4 waves as 2x2 over 128x128 tile).
__global__ __launch_bounds__(256) void qkv_gemm(
    const short* __restrict__ xb, const short* __restrict__ Wqb,
    const short* __restrict__ Wkb, const short* __restrict__ Wvb,
    short* __restrict__ Qb, short* __restrict__ Kb, short* __restrict__ VTb)
{
  const int z = blockIdx.z;
  const short* W = (z == 0) ? Wqb : (z == 1) ? Wkb : Wvb;
  const int lane = threadIdx.x & 63;
  const int wv = threadIdx.x >> 6;
  const int quad = lane >> 4, lq = lane & 15;
  const int m0 = blockIdx.y * 128 + (wv & 1) * 64;
  const int n0 = blockIdx.x * 128 + (wv >> 1) * 64;
  f32x4 acc[4][4] = {};
  gemm_core_64(xb, W, m0, n0, lq, quad, acc);
#pragma unroll
  for (int mt = 0; mt < 4; ++mt)
#pragma unroll
    for (int nt = 0; nt < 4; ++nt)
#pragma unroll
      for (int r = 0; r < 4; ++r) {
        const int m = m0 + mt * 16 + quad * 4 + r;       // C/D: row = quad*4+reg
        const int n = n0 + nt * 16 + lq;                 // C/D: col = lane&15
        const int b = m >> 11, s = m & 2047;
        const int h = n >> 6, d = n & 63;
        const short v = f2bf(acc[mt][nt][r]);
        if (z == 0)      Qb[((size_t)(b * NH + h) * SEQ + s) * HD + d] = v;
        else if (z == 1) Kb[((size_t)(b * NH + h) * SEQ + s) * HD + d] = v;
        else             VTb[((size_t)(b * NH + h) * HD + d) * SEQ + s] = v; // V^T
      }
}

// ------------------------------------------------------------ flash attention
// Transposed-softmax flash attention, no LDS, no __syncthreads.
// grid (768): block = 48 bh-slices * 16 balance-pairs; 4 waves, each owns 32 queries.
// S^T = K.Q^T via mfma(K_frag, Q_frag): lane lq owns query wq+qt*16+lq.
// K rows loaded permuted so P lands directly in PV B-operand layout.
__global__ __launch_bounds__(256) void attn_kernel(
    const short* __restrict__ Qb, const short* __restrict__ Kb,
    const short* __restrict__ VTb, short* __restrict__ AOb)
{
  const int bp = blockIdx.x;
  const int bh = bp % 48;          // all 4 waves share (b,h) for K/V locality
  const int p  = bp / 48;          // 0..15 balance pair index
  const int w  = threadIdx.x >> 6;
  const int lane = threadIdx.x & 63;
  const int quad = lane >> 4, lq = lane & 15;
  // balanced causal work: tiles {2p, 63-2p, 2p+1, 62-2p} (pair sums equal)
  int tile;
  if (w == 0) tile = 2 * p;
  else if (w == 1) tile = 63 - 2 * p;
  else if (w == 2) tile = 2 * p + 1;
  else tile = 62 - 2 * p;
  const int wq = tile * 32;
  const int b = bh / NH, h = bh % NH;

  const short* Qh = Qb  + (size_t)bh * SEQ * HD;
  const short* Kh = Kb  + (size_t)bh * SEQ * HD;
  const short* Vh = VTb + (size_t)bh * HD * SEQ;

  // Q fragments (B-operand of S^T): lane holds Q[wq+qt*16+lq][hh*32+quad*8+j]
  bf16x8 qf[2][2];
#pragma unroll
  for (int qt = 0; qt < 2; ++qt)
#pragma unroll
    for (int hh = 0; hh < 2; ++hh)
      qf[qt][hh] = *(const bf16x8*)(Qh + (size_t)(wq + qt * 16 + lq) * HD + hh * 32 + quad * 8);

  f32x4 o[4][2] = {};              // O^T[hd=mt*16+quad*4+r][q=wq+qt*16+lq]
  float m_[2] = {-3e38f, -3e38f};
  float l_[2] = {0.0f, 0.0f};
  const float C = 0.18033688011112042f;   // log2(e)/sqrt(64)

  const int kend = wq + 32;
  for (int kb = 0; kb < kend; kb += 64) {
    // ---- S^T = K.Q^T over 64 keys (2 windows of 32, 2 permuted 16-row tiles each)
    f32x4 st[2][2][2] = {};        // [window][t][qt]
#pragma unroll
    for (int wd = 0; wd < 2; ++wd)
#pragma unroll
      for (int t = 0; t < 2; ++t) {
        const int krow = kb + 32 * wd + 8 * (lq >> 2) + 4 * t + (lq & 3);
        const short* kp = Kh + (size_t)krow * HD + quad * 8;
        bf16x8 k0 = *(const bf16x8*)(kp);
        bf16x8 k1 = *(const bf16x8*)(kp + 32);
        st[wd][t][0] = __builtin_amdgcn_mfma_f32_16x16x32_bf16(k0, qf[0][0], st[wd][t][0], 0, 0, 0);
        st[wd][t][0] = __builtin_amdgcn_mfma_f32_16x16x32_bf16(k1, qf[0][1], st[wd][t][0], 0, 0, 0);
        st[wd][t][1] = __builtin_amdgcn_mfma_f32_16x16x32_bf16(k0, qf[1][0], st[wd][t][1], 0, 0, 0);
        st[wd][t][1] = __builtin_amdgcn_mfma_f32_16x16x32_bf16(k1, qf[1][1], st[wd][t][1], 0, 0, 0);
      }

    // ---- causal mask + running max (lane's key for [wd][t][r] = kb+32wd+8quad+4t+r)
    float mx[2] = {-3e38f, -3e38f};
#pragma unroll
    for (int wd = 0; wd < 2; ++wd)
#pragma unroll
      for (int t = 0; t < 2; ++t)
#pragma unroll
        for (int qt = 0; qt < 2; ++qt)
#pragma unroll
          for (int r = 0; r < 4; ++r) {
            const int key = kb + 32 * wd + 8 * quad + 4 * t + r;
            const int q   = wq + qt * 16 + lq;
            const float v = (key <= q) ? st[wd][t][qt][r] : -3e38f;
            st[wd][t][qt][r] = v;
            mx[qt] = fmaxf(mx[qt], v);
          }
#pragma unroll
    for (int qt = 0; qt < 2; ++qt) {
      mx[qt] = fmaxf(mx[qt], __shfl_xor(mx[qt], 16));
      mx[qt] = fmaxf(mx[qt], __shfl_xor(mx[qt], 32));
    }

    float alpha[2], rs[2] = {0.0f, 0.0f};
#pragma unroll
    for (int qt = 0; qt < 2; ++qt) {
      const float mn = fmaxf(m_[qt], mx[qt]);
      alpha[qt] = __builtin_amdgcn_exp2f((m_[qt] - mn) * C);
      m_[qt] = mn;
    }
    // ---- exp (scale folded into C), in-register sums
#pragma unroll
    for (int wd = 0; wd < 2; ++wd)
#pragma unroll
      for (int t = 0; t < 2; ++t)
#pragma unroll
        for (int qt = 0; qt < 2; ++qt)
#pragma unroll
          for (int r = 0; r < 4; ++r) {
            const float pv = __builtin_amdgcn_exp2f((st[wd][t][qt][r] - m_[qt]) * C);
            st[wd][t][qt][r] = pv;
            rs[qt] += pv;
          }
#pragma unroll
    for (int qt = 0; qt < 2; ++qt) {
      rs[qt] += __shfl_xor(rs[qt], 16);
      rs[qt] += __shfl_xor(rs[qt], 32);
      l_[qt] = l_[qt] * alpha[qt] + rs[qt];
    }
    // ---- rescale accumulator
#pragma unroll
    for (int mt = 0; mt < 4; ++mt)
#pragma unroll
      for (int qt = 0; qt < 2; ++qt)
#pragma unroll
        for (int r = 0; r < 4; ++r)
          o[mt][qt][r] *= alpha[qt];

    // ---- pack P directly into PV B-operand layout (keys quad*8+j per lane)
    bf16x8 pf[2][2];
#pragma unroll
    for (int wd = 0; wd < 2; ++wd)
#pragma unroll
      for (int qt = 0; qt < 2; ++qt) {
        bf16x8 f;
#pragma unroll
        for (int r = 0; r < 4; ++r) {
          f[r]     = f2bf(st[wd][0][qt][r]);
          f[r + 4] = f2bf(st[wd][1][qt][r]);
        }
        pf[wd][qt] = f;
      }

    // ---- O^T += V^T . P^T  (A = V^T rows of hd, contiguous keys)
#pragma unroll
    for (int wd = 0; wd < 2; ++wd)
#pragma unroll
      for (int mt = 0; mt < 4; ++mt) {
        bf16x8 vf = *(const bf16x8*)(Vh + (size_t)(mt * 16 + lq) * SEQ + kb + 32 * wd + quad * 8);
        o[mt][0] = __builtin_amdgcn_mfma_f32_16x16x32_bf16(vf, pf[wd][0], o[mt][0], 0, 0, 0);
        o[mt][1] = __builtin_amdgcn_mfma_f32_16x16x32_bf16(vf, pf[wd][1], o[mt][1], 0, 0, 0);
      }
  }

  // ---- epilogue: O^T[hd][q] / l  -> AO[(b,s),(h,d)]
#pragma unroll
  for (int qt = 0; qt < 2; ++qt) {
    const float inv = 1.0f / l_[qt];
    const int q = wq + qt * 16 + lq;
#pragma unroll
    for (int mt = 0; mt < 4; ++mt) {
      short4 v;
      v.x = f2bf(o[mt][qt][0] * inv);
      v.y = f2bf(o[mt][qt][1] * inv);
      v.z = f2bf(o[mt][qt][2] * inv);
      v.w = f2bf(o[mt][qt][3] * inv);
      *(short4*)(AOb + ((size_t)(b * SEQ + q)) * DM + h * HD + mt * 16 + quad * 4) = v;
    }
  }
}

// ----------------------------------------------------------- output projection
__global__ __launch_bounds__(256) void out_gemm(
    const short* __restrict__ AOb, const short* __restrict__ Wob, float* __restrict__ C)
{
  const int lane = threadIdx.x & 63;
  const int wv = threadIdx.x >> 6;
  const int quad = lane >> 4, lq = lane & 15;
  const int m0 = blockIdx.y * 128 + (wv & 1) * 64;
  const int n0 = blockIdx.x * 128 + (wv >> 1) * 64;
  f32x4 acc[4][4] = {};
  gemm_core_64(AOb, Wob, m0, n0, lq, quad, acc);
#pragma unroll
  for (int mt = 0; mt < 4; ++mt)
#pragma unroll
    for (int nt = 0; nt < 4; ++nt)
#pragma unroll
      for (int r = 0; r < 4; ++r) {
        const int m = m0 + mt * 16 + quad * 4 + r;
        const int n = n0 + nt * 16 + lq;
        C[(size_t)m * DM + n] = acc[mt][nt][r];
      }
}

// ------------------------------------------------------------------- launcher
extern "C" void kernel_launch(void* const* d_in, const int* in_sizes, int n_in,
                              void* d_out, int out_size, void* d_ws, size_t ws_size,
                              hipStream_t stream) {
  const float* x  = (const float*)d_in[0];
  const float* Wq = (const float*)d_in[1];
  const float* Wk = (const float*)d_in[2];
  const float* Wv = (const float*)d_in[3];
  const float* Wo = (const float*)d_in[4];
  float* out = (float*)d_out;

  // workspace layout (bf16 shorts), ~55 MB total
  short* xb  = (short*)d_ws;                       // 8192*768
  short* Wqb = xb  + (size_t)MTOT * DM;
  short* Wkb = Wqb + DM * DM;
  short* Wvb = Wkb + DM * DM;
  short* Wob = Wvb + DM * DM;
  short* Qb  = Wob + DM * DM;                      // (b,h,s,d)
  short* Kb  = Qb  + (size_t)MTOT * DM;            // (b,h,s,d)
  short* VTb = Kb  + (size_t)MTOT * DM;            // (b,h,d,s)
  short* AOb = xb;                                 // alias: xb dead after qkv_gemm

  cvt_kernel<<<(MTOT * DM / 4 + 255) / 256, 256, 0, stream>>>(x, xb, MTOT * DM / 4);
  cvt_kernel<<<(DM * DM / 4 + 255) / 256, 256, 0, stream>>>(Wq, Wqb, DM * DM / 4);
  cvt_kernel<<<(DM * DM / 4 + 255) / 256, 256, 0, stream>>>(Wk, Wkb, DM * DM / 4);
  cvt_kernel<<<(DM * DM / 4 + 255) / 256, 256, 0, stream>>>(Wv, Wvb, DM * DM / 4);
  cvt_kernel<<<(DM * DM / 4 + 255) / 256, 256, 0, stream>>>(Wo, Wob, DM * DM / 4);

  qkv_gemm<<<dim3(DM / 128, MTOT / 128, 3), 256, 0, stream>>>(xb, Wqb, Wkb, Wvb, Qb, Kb, VTb);
  attn_kernel<<<dim3(768), 256, 0, stream>>>(Qb, Kb, VTb, AOb);
  out_gemm<<<dim3(DM / 128, MTOT / 128), 256, 0, stream>>>(AOb, Wob, out);
}

// Round 3
// 258.722 us; speedup vs baseline: 2.6976x; 1.3792x over previous
//
#include <hip/hip_runtime.h>
#include <hip/hip_bf16.h>

// Problem constants
#define SEQ   2048
#define BATCH 4
#define DM    768
#define NH    12
#define HD    64
#define MTOT  (BATCH*SEQ)   // 8192

typedef short bf16x8 __attribute__((ext_vector_type(8)));   // 8 bf16 = 4 VGPRs
typedef float f32x4  __attribute__((ext_vector_type(4)));

static __device__ __forceinline__ short f2bf(float f) {
  union { __hip_bfloat16 h; short s; } u;
  u.h = __float2bfloat16(f);
  return u.s;
}

// async global->LDS, 16 B per lane (global_load_lds_dwordx4)
static __device__ __forceinline__ void async_cp16(const short* g, short* l) {
  __builtin_amdgcn_global_load_lds(
      (const __attribute__((address_space(1))) void*)g,
      (__attribute__((address_space(3))) void*)l, 16, 0, 0);
}

// ---------------------------------------------------------------- fp32 -> bf16
__global__ void cvt_kernel(const float* __restrict__ in, short* __restrict__ out, int n4) {
  int i = blockIdx.x * blockDim.x + threadIdx.x;
  if (i >= n4) return;
  float4 v = reinterpret_cast<const float4*>(in)[i];
  short4 o;
  o.x = f2bf(v.x); o.y = f2bf(v.y); o.z = f2bf(v.z); o.w = f2bf(v.w);
  reinterpret_cast<short4*>(out)[i] = o;
}

// ---------------------------------------------- m97-style 128x128 LDS-staged GEMM core
// C[m][n] = sum_k A[m][k] * W[n][k]  (both row-major, K contiguous). BK=32.
// Block 256 = 4 waves as 2x2 over the 128x128 tile; 64x64 per wave (4x4 MFMA acc).
static __device__ __forceinline__ void gemm_lds_core(
    const short* __restrict__ A, const short* __restrict__ W,
    short* As, short* Bs, int m0, int n0, f32x4 acc[4][4])
{
  const int t = threadIdx.x;
  const int lane = t & 63, w = t >> 6;
  const int quad = lane >> 4, lq = lane & 15;
  const int mw = (w & 1) * 64, nw = (w >> 1) * 64;
  // staging map: thread t loads 16B chunk (t&3) of row (t>>2); chunk1 = rows +64
  const int r0 = t >> 2, c0 = (t & 3) * 8;
  const short* ga0 = A + (size_t)(m0 + r0) * DM + c0;
  const short* ga1 = A + (size_t)(m0 + 64 + r0) * DM + c0;
  const short* gb0 = W + (size_t)(n0 + r0) * DM + c0;
  const short* gb1 = W + (size_t)(n0 + 64 + r0) * DM + c0;
  short* la0 = As + t * 8;           // byte offset t*16
  short* la1 = As + 2048 + t * 8;    // rows 64..127 start at byte 4096
  short* lb0 = Bs + t * 8;
  short* lb1 = Bs + 2048 + t * 8;

  for (int k0 = 0; k0 < DM; k0 += 32) {
    async_cp16(ga0 + k0, la0);
    async_cp16(ga1 + k0, la1);
    async_cp16(gb0 + k0, lb0);
    async_cp16(gb1 + k0, lb1);
    __syncthreads();                 // compiler emits vmcnt(0) drain before barrier
    bf16x8 af[4], bf[4];
#pragma unroll
    for (int i = 0; i < 4; ++i) {
      af[i] = *(const bf16x8*)(As + (mw + i * 16 + lq) * 32 + quad * 8);
      bf[i] = *(const bf16x8*)(Bs + (nw + i * 16 + lq) * 32 + quad * 8);
    }
#pragma unroll
    for (int mt = 0; mt < 4; ++mt)
#pragma unroll
      for (int nt = 0; nt < 4; ++nt)
        acc[mt][nt] = __builtin_amdgcn_mfma_f32_16x16x32_bf16(af[mt], bf[nt], acc[mt][nt], 0, 0, 0);
    __syncthreads();
  }
}

// --------------------------------------------------------------- fused QKV projection
// Wq/Wk/Wv contiguous in ws -> one GEMM M=8192, N=2304, K=768.
// grid (18, 64), block 256. Output scattered to Q(b,h,s,d), K(b,h,s,d), V^T(b,h,d,s).
__global__ __launch_bounds__(256) void qkv_gemm(
    const short* __restrict__ xb, const short* __restrict__ Wall,
    short* __restrict__ Qb, short* __restrict__ Kb, short* __restrict__ VTb)
{
  __shared__ __align__(16) short As[4096], Bs[4096];
  const int m0 = blockIdx.y * 128, n0 = blockIdx.x * 128;
  f32x4 acc[4][4] = {};
  gemm_lds_core(xb, Wall, As, Bs, m0, n0, acc);

  const int t = threadIdx.x;
  const int lane = t & 63, w = t >> 6;
  const int quad = lane >> 4, lq = lane & 15;
  const int mwb = m0 + (w & 1) * 64, nwb = n0 + (w >> 1) * 64;
#pragma unroll
  for (int mt = 0; mt < 4; ++mt)
#pragma unroll
    for (int nt = 0; nt < 4; ++nt) {
      const int n = nwb + nt * 16 + lq;            // C/D col = lane&15
      const int z = n / DM, nn = n % DM;           // block never straddles z (128 | 768)
      const int h = nn >> 6, d = nn & 63;
      const int mbase = mwb + mt * 16 + quad * 4;  // C/D row = quad*4+r
      const int b = mbase >> 11, s0 = mbase & 2047;
      if (z == 2) {                                // V^T: 4 consecutive s per lane
        short4 v;
        v.x = f2bf(acc[mt][nt][0]); v.y = f2bf(acc[mt][nt][1]);
        v.z = f2bf(acc[mt][nt][2]); v.w = f2bf(acc[mt][nt][3]);
        *(short4*)(VTb + ((size_t)(b * NH + h) * HD + d) * SEQ + s0) = v;
      } else {
        short* dst = (z == 0) ? Qb : Kb;
#pragma unroll
        for (int r = 0; r < 4; ++r)
          dst[((size_t)(b * NH + h) * SEQ + s0 + r) * HD + d] = f2bf(acc[mt][nt][r]);
      }
    }
}

// ------------------------------------------------------------ flash attention
// Transposed-softmax flash attention, no LDS, no __syncthreads.
// grid (768): block = 48 bh-slices * 16 balance-pairs; 4 waves, each owns 32 queries.
__global__ __launch_bounds__(256) void attn_kernel(
    const short* __restrict__ Qb, const short* __restrict__ Kb,
    const short* __restrict__ VTb, short* __restrict__ AOb)
{
  const int bp = blockIdx.x;
  const int bh = bp % 48;          // all 4 waves share (b,h) for K/V locality
  const int p  = bp / 48;          // 0..15 balance pair index
  const int w  = threadIdx.x >> 6;
  const int lane = threadIdx.x & 63;
  const int quad = lane >> 4, lq = lane & 15;
  int tile;
  if (w == 0) tile = 2 * p;
  else if (w == 1) tile = 63 - 2 * p;
  else if (w == 2) tile = 2 * p + 1;
  else tile = 62 - 2 * p;
  const int wq = tile * 32;
  const int b = bh / NH, h = bh % NH;

  const short* Qh = Qb  + (size_t)bh * SEQ * HD;
  const short* Kh = Kb  + (size_t)bh * SEQ * HD;
  const short* Vh = VTb + (size_t)bh * HD * SEQ;

  bf16x8 qf[2][2];
#pragma unroll
  for (int qt = 0; qt < 2; ++qt)
#pragma unroll
    for (int hh = 0; hh < 2; ++hh)
      qf[qt][hh] = *(const bf16x8*)(Qh + (size_t)(wq + qt * 16 + lq) * HD + hh * 32 + quad * 8);

  f32x4 o[4][2] = {};              // O^T[hd=mt*16+quad*4+r][q=wq+qt*16+lq]
  float m_[2] = {-3e38f, -3e38f};
  float l_[2] = {0.0f, 0.0f};
  const float C = 0.18033688011112042f;   // log2(e)/sqrt(64)

  const int kend = wq + 32;
  for (int kb = 0; kb < kend; kb += 64) {
    f32x4 st[2][2][2] = {};        // [window][t][qt]
#pragma unroll
    for (int wd = 0; wd < 2; ++wd)
#pragma unroll
      for (int t = 0; t < 2; ++t) {
        const int krow = kb + 32 * wd + 8 * (lq >> 2) + 4 * t + (lq & 3);
        const short* kp = Kh + (size_t)krow * HD + quad * 8;
        bf16x8 k0 = *(const bf16x8*)(kp);
        bf16x8 k1 = *(const bf16x8*)(kp + 32);
        st[wd][t][0] = __builtin_amdgcn_mfma_f32_16x16x32_bf16(k0, qf[0][0], st[wd][t][0], 0, 0, 0);
        st[wd][t][0] = __builtin_amdgcn_mfma_f32_16x16x32_bf16(k1, qf[0][1], st[wd][t][0], 0, 0, 0);
        st[wd][t][1] = __builtin_amdgcn_mfma_f32_16x16x32_bf16(k0, qf[1][0], st[wd][t][1], 0, 0, 0);
        st[wd][t][1] = __builtin_amdgcn_mfma_f32_16x16x32_bf16(k1, qf[1][1], st[wd][t][1], 0, 0, 0);
      }

    float mx[2] = {-3e38f, -3e38f};
#pragma unroll
    for (int wd = 0; wd < 2; ++wd)
#pragma unroll
      for (int t = 0; t < 2; ++t)
#pragma unroll
        for (int qt = 0; qt < 2; ++qt)
#pragma unroll
          for (int r = 0; r < 4; ++r) {
            const int key = kb + 32 * wd + 8 * quad + 4 * t + r;
            const int q   = wq + qt * 16 + lq;
            const float v = (key <= q) ? st[wd][t][qt][r] : -3e38f;
            st[wd][t][qt][r] = v;
            mx[qt] = fmaxf(mx[qt], v);
          }
#pragma unroll
    for (int qt = 0; qt < 2; ++qt) {
      mx[qt] = fmaxf(mx[qt], __shfl_xor(mx[qt], 16));
      mx[qt] = fmaxf(mx[qt], __shfl_xor(mx[qt], 32));
    }

    float alpha[2], rs[2] = {0.0f, 0.0f};
#pragma unroll
    for (int qt = 0; qt < 2; ++qt) {
      const float mn = fmaxf(m_[qt], mx[qt]);
      alpha[qt] = __builtin_amdgcn_exp2f((m_[qt] - mn) * C);
      m_[qt] = mn;
    }
#pragma unroll
    for (int wd = 0; wd < 2; ++wd)
#pragma unroll
      for (int t = 0; t < 2; ++t)
#pragma unroll
        for (int qt = 0; qt < 2; ++qt)
#pragma unroll
          for (int r = 0; r < 4; ++r) {
            const float pv = __builtin_amdgcn_exp2f((st[wd][t][qt][r] - m_[qt]) * C);
            st[wd][t][qt][r] = pv;
            rs[qt] += pv;
          }
#pragma unroll
    for (int qt = 0; qt < 2; ++qt) {
      rs[qt] += __shfl_xor(rs[qt], 16);
      rs[qt] += __shfl_xor(rs[qt], 32);
      l_[qt] = l_[qt] * alpha[qt] + rs[qt];
    }
#pragma unroll
    for (int mt = 0; mt < 4; ++mt)
#pragma unroll
      for (int qt = 0; qt < 2; ++qt)
#pragma unroll
        for (int r = 0; r < 4; ++r)
          o[mt][qt][r] *= alpha[qt];

    bf16x8 pf[2][2];
#pragma unroll
    for (int wd = 0; wd < 2; ++wd)
#pragma unroll
      for (int qt = 0; qt < 2; ++qt) {
        bf16x8 f;
#pragma unroll
        for (int r = 0; r < 4; ++r) {
          f[r]     = f2bf(st[wd][0][qt][r]);
          f[r + 4] = f2bf(st[wd][1][qt][r]);
        }
        pf[wd][qt] = f;
      }

#pragma unroll
    for (int wd = 0; wd < 2; ++wd)
#pragma unroll
      for (int mt = 0; mt < 4; ++mt) {
        bf16x8 vf = *(const bf16x8*)(Vh + (size_t)(mt * 16 + lq) * SEQ + kb + 32 * wd + quad * 8);
        o[mt][0] = __builtin_amdgcn_mfma_f32_16x16x32_bf16(vf, pf[wd][0], o[mt][0], 0, 0, 0);
        o[mt][1] = __builtin_amdgcn_mfma_f32_16x16x32_bf16(vf, pf[wd][1], o[mt][1], 0, 0, 0);
      }
  }

#pragma unroll
  for (int qt = 0; qt < 2; ++qt) {
    const float inv = 1.0f / l_[qt];
    const int q = wq + qt * 16 + lq;
#pragma unroll
    for (int mt = 0; mt < 4; ++mt) {
      short4 v;
      v.x = f2bf(o[mt][qt][0] * inv);
      v.y = f2bf(o[mt][qt][1] * inv);
      v.z = f2bf(o[mt][qt][2] * inv);
      v.w = f2bf(o[mt][qt][3] * inv);
      *(short4*)(AOb + ((size_t)(b * SEQ + q)) * DM + h * HD + mt * 16 + quad * 4) = v;
    }
  }
}

// ----------------------------------------------------------- output projection
__global__ __launch_bounds__(256) void out_gemm(
    const short* __restrict__ AOb, const short* __restrict__ Wob, float* __restrict__ C)
{
  __shared__ __align__(16) short As[4096], Bs[4096];
  const int m0 = blockIdx.y * 128, n0 = blockIdx.x * 128;
  f32x4 acc[4][4] = {};
  gemm_lds_core(AOb, Wob, As, Bs, m0, n0, acc);

  const int t = threadIdx.x;
  const int lane = t & 63, w = t >> 6;
  const int quad = lane >> 4, lq = lane & 15;
  const int mwb = m0 + (w & 1) * 64, nwb = n0 + (w >> 1) * 64;
#pragma unroll
  for (int mt = 0; mt < 4; ++mt)
#pragma unroll
    for (int nt = 0; nt < 4; ++nt) {
      const int n = nwb + nt * 16 + lq;
      const int mbase = mwb + mt * 16 + quad * 4;
#pragma unroll
      for (int r = 0; r < 4; ++r)
        C[(size_t)(mbase + r) * DM + n] = acc[mt][nt][r];
    }
}

// ------------------------------------------------------------------- launcher
extern "C" void kernel_launch(void* const* d_in, const int* in_sizes, int n_in,
                              void* d_out, int out_size, void* d_ws, size_t ws_size,
                              hipStream_t stream) {
  const float* x  = (const float*)d_in[0];
  const float* Wq = (const float*)d_in[1];
  const float* Wk = (const float*)d_in[2];
  const float* Wv = (const float*)d_in[3];
  const float* Wo = (const float*)d_in[4];
  float* out = (float*)d_out;

  // workspace layout (bf16 shorts), ~55 MB total. Wq/Wk/Wv contiguous => fused N=2304.
  short* xb  = (short*)d_ws;                       // 8192*768
  short* Wqb = xb  + (size_t)MTOT * DM;
  short* Wkb = Wqb + DM * DM;
  short* Wvb = Wkb + DM * DM;
  short* Wob = Wvb + DM * DM;
  short* Qb  = Wob + DM * DM;                      // (b,h,s,d)
  short* Kb  = Qb  + (size_t)MTOT * DM;            // (b,h,s,d)
  short* VTb = Kb  + (size_t)MTOT * DM;            // (b,h,d,s)
  short* AOb = xb;                                 // alias: xb dead after qkv_gemm

  cvt_kernel<<<(MTOT * DM / 4 + 255) / 256, 256, 0, stream>>>(x, xb, MTOT * DM / 4);
  cvt_kernel<<<(DM * DM / 4 + 255) / 256, 256, 0, stream>>>(Wq, Wqb, DM * DM / 4);
  cvt_kernel<<<(DM * DM / 4 + 255) / 256, 256, 0, stream>>>(Wk, Wkb, DM * DM / 4);
  cvt_kernel<<<(DM * DM / 4 + 255) / 256, 256, 0, stream>>>(Wv, Wvb, DM * DM / 4);
  cvt_kernel<<<(DM * DM / 4 + 255) / 256, 256, 0, stream>>>(Wo, Wob, DM * DM / 4);

  qkv_gemm<<<dim3(3 * DM / 128, MTOT / 128), 256, 0, stream>>>(xb, Wqb, Qb, Kb, VTb);
  attn_kernel<<<dim3(768), 256, 0, stream>>>(Qb, Kb, VTb, AOb);
  out_gemm<<<dim3(DM / 128, MTOT / 128), 256, 0, stream>>>(AOb, Wob, out);
}

// Round 5
// 240.997 us; speedup vs baseline: 2.8960x; 1.0735x over previous
//
#include <hip/hip_runtime.h>
#include <hip/hip_bf16.h>

// Problem constants
#define SEQ   2048
#define BATCH 4
#define DM    768
#define NH    12
#define HD    64
#define MTOT  (BATCH*SEQ)   // 8192

typedef short bf16x8 __attribute__((ext_vector_type(8)));   // 8 bf16 = 4 VGPRs
typedef float f32x4  __attribute__((ext_vector_type(4)));

static __device__ __forceinline__ short f2bf(float f) {
  union { __hip_bfloat16 h; short s; } u;
  u.h = __float2bfloat16(f);
  return u.s;
}

// async global->LDS, 16 B per lane (global_load_lds_dwordx4)
static __device__ __forceinline__ void async_cp16(const short* g, short* l) {
  __builtin_amdgcn_global_load_lds(
      (const __attribute__((address_space(1))) void*)g,
      (__attribute__((address_space(3))) void*)l, 16, 0, 0);
}

// ------------------------------------------- fused fp32 -> bf16 (x + 4 weights)
__global__ void cvt5_kernel(const float* __restrict__ x, const float* __restrict__ wq,
                            const float* __restrict__ wk, const float* __restrict__ wv,
                            const float* __restrict__ wo, short* __restrict__ dst) {
  const int NX4 = MTOT * DM / 4, NW4 = DM * DM / 4, TOT4 = NX4 + 4 * NW4;
  int i = blockIdx.x * blockDim.x + threadIdx.x;
  if (i >= TOT4) return;
  const float* src; int off;
  if (i < NX4) { src = x; off = i; }
  else {
    int j = i - NX4; int sel = j / NW4; off = j - sel * NW4;
    src = (sel == 0) ? wq : (sel == 1) ? wk : (sel == 2) ? wv : wo;
  }
  float4 v = reinterpret_cast<const float4*>(src)[off];
  short4 o;
  o.x = f2bf(v.x); o.y = f2bf(v.y); o.z = f2bf(v.z); o.w = f2bf(v.w);
  reinterpret_cast<short4*>(dst)[i] = o;
}

// ---------------------------------------------- m97-style 128x128 LDS-staged GEMM core
static __device__ __forceinline__ void gemm_lds_core(
    const short* __restrict__ A, const short* __restrict__ W,
    short* As, short* Bs, int m0, int n0, f32x4 acc[4][4])
{
  const int t = threadIdx.x;
  const int lane = t & 63, w = t >> 6;
  const int quad = lane >> 4, lq = lane & 15;
  const int mw = (w & 1) * 64, nw = (w >> 1) * 64;
  const int r0 = t >> 2, c0 = (t & 3) * 8;
  const short* ga0 = A + (size_t)(m0 + r0) * DM + c0;
  const short* ga1 = A + (size_t)(m0 + 64 + r0) * DM + c0;
  const short* gb0 = W + (size_t)(n0 + r0) * DM + c0;
  const short* gb1 = W + (size_t)(n0 + 64 + r0) * DM + c0;
  short* la0 = As + t * 8;
  short* la1 = As + 2048 + t * 8;
  short* lb0 = Bs + t * 8;
  short* lb1 = Bs + 2048 + t * 8;

  for (int k0 = 0; k0 < DM; k0 += 32) {
    async_cp16(ga0 + k0, la0);
    async_cp16(ga1 + k0, la1);
    async_cp16(gb0 + k0, lb0);
    async_cp16(gb1 + k0, lb1);
    __syncthreads();
    bf16x8 af[4], bf[4];
#pragma unroll
    for (int i = 0; i < 4; ++i) {
      af[i] = *(const bf16x8*)(As + (mw + i * 16 + lq) * 32 + quad * 8);
      bf[i] = *(const bf16x8*)(Bs + (nw + i * 16 + lq) * 32 + quad * 8);
    }
#pragma unroll
    for (int mt = 0; mt < 4; ++mt)
#pragma unroll
      for (int nt = 0; nt < 4; ++nt)
        acc[mt][nt] = __builtin_amdgcn_mfma_f32_16x16x32_bf16(af[mt], bf[nt], acc[mt][nt], 0, 0, 0);
    __syncthreads();
  }
}

// --------------------------------------------------------------- fused QKV projection
__global__ __launch_bounds__(256) void qkv_gemm(
    const short* __restrict__ xb, const short* __restrict__ Wall,
    short* __restrict__ Qb, short* __restrict__ Kb, short* __restrict__ VTb)
{
  __shared__ __align__(16) short As[4096], Bs[4096];
  const int m0 = blockIdx.y * 128, n0 = blockIdx.x * 128;
  f32x4 acc[4][4] = {};
  gemm_lds_core(xb, Wall, As, Bs, m0, n0, acc);

  const int t = threadIdx.x;
  const int lane = t & 63, w = t >> 6;
  const int quad = lane >> 4, lq = lane & 15;
  const int mwb = m0 + (w & 1) * 64, nwb = n0 + (w >> 1) * 64;
#pragma unroll
  for (int mt = 0; mt < 4; ++mt)
#pragma unroll
    for (int nt = 0; nt < 4; ++nt) {
      const int n = nwb + nt * 16 + lq;
      const int z = n / DM, nn = n % DM;
      const int h = nn >> 6, d = nn & 63;
      const int mbase = mwb + mt * 16 + quad * 4;
      const int b = mbase >> 11, s0 = mbase & 2047;
      if (z == 2) {
        short4 v;
        v.x = f2bf(acc[mt][nt][0]); v.y = f2bf(acc[mt][nt][1]);
        v.z = f2bf(acc[mt][nt][2]); v.w = f2bf(acc[mt][nt][3]);
        *(short4*)(VTb + ((size_t)(b * NH + h) * HD + d) * SEQ + s0) = v;
      } else {
        short* dst = (z == 0) ? Qb : Kb;
#pragma unroll
        for (int r = 0; r < 4; ++r)
          dst[((size_t)(b * NH + h) * SEQ + s0 + r) * HD + d] = f2bf(acc[mt][nt][r]);
      }
    }
}

// ------------------------------------------------------------ flash attention
// Pair-balanced + block-cooperative LDS K/V staging; round-3-exact softmax
// (unconditional mask, unconditional alpha rescale, per-step reduced rowsum,
// fully inlined — no lambda, no address-taken register arrays in helpers).
// grid(768): bh = bp%48, g = bp/48. Wave w owns pair tp=4g+w: query tiles
// [16tp,16tp+16) (qt0) and [2032-16tp, 2048-16tp) (qt1).
__global__ __launch_bounds__(256) void attn_kernel(
    const short* __restrict__ Qb, const short* __restrict__ Kb,
    const short* __restrict__ VTb, short* __restrict__ AOb)
{
  __shared__ __align__(16) short Ks[32 * 64];   // [keyoff][hd]
  __shared__ __align__(16) short Vs[64 * 32];   // [hd][keyoff]
  const int bp = blockIdx.x;
  const int bh = bp % 48;
  const int g  = bp / 48;              // 0..15
  const int tid = threadIdx.x;
  const int w = tid >> 6, lane = tid & 63;
  const int quad = lane >> 4, lq = lane & 15;
  const int tp = 4 * g + w;            // pair id 0..63
  const int b = bh / NH, h = bh % NH;
  const int q0b = 16 * tp;             // qt0 query base
  const int q1b = 2032 - 16 * tp;      // qt1 query base
  const int E0 = q0b + 16;             // qt0 key range end
  const int E1 = q1b + 16;             // qt1 key range end
  const int Eblk = 2048 - 64 * g;      // block-uniform loop bound (= E1 of w=0)

  const short* Qh = Qb  + (size_t)bh * SEQ * HD;
  const short* Kh = Kb  + (size_t)bh * SEQ * HD;
  const short* Vh = VTb + (size_t)bh * HD * SEQ;

  // Q fragments (B-operand): lane holds Q[qb+lq][hh*32+quad*8+j]
  bf16x8 qf0[2], qf1[2];
#pragma unroll
  for (int hh = 0; hh < 2; ++hh) {
    qf0[hh] = *(const bf16x8*)(Qh + (size_t)(q0b + lq) * HD + hh * 32 + quad * 8);
    qf1[hh] = *(const bf16x8*)(Qh + (size_t)(q1b + lq) * HD + hh * 32 + quad * 8);
  }

  f32x4 o0[4] = {}, o1[4] = {};        // O^T[hd=mt*16+quad*4+r][q=qb+lq]
  float m0v = -3e38f, m1v = -3e38f;
  float l0v = 0.0f, l1v = 0.0f;        // full per-lane l (round-3 semantics)
  const float Cc = 0.18033688011112042f;  // log2(e)/sqrt(64)

  // staging maps (wave-uniform base + lane*16B, per global_load_lds rule)
  const short* gK = Kh + (size_t)(tid >> 3) * HD + (tid & 7) * 8;
  const short* gV = Vh + (size_t)(tid >> 2) * SEQ + (tid & 3) * 8;
  short* lK = Ks + tid * 8;
  short* lV = Vs + tid * 8;

  for (int kb = 0; kb < Eblk; kb += 32) {
    async_cp16(gK + (size_t)kb * HD, lK);
    async_cp16(gV + kb, lV);
    __syncthreads();
    if (kb < E1) {
      const bool act0 = kb < E0;
      // ---- S^T = K.Q^T (K rows permuted so P exits in PV B-operand layout)
      f32x4 st0[2] = {}, st1[2] = {};
#pragma unroll
      for (int t2 = 0; t2 < 2; ++t2) {
        const int row = 8 * (lq >> 2) + 4 * t2 + (lq & 3);
        bf16x8 k0 = *(const bf16x8*)(Ks + row * 64 + quad * 8);
        bf16x8 k1 = *(const bf16x8*)(Ks + row * 64 + 32 + quad * 8);
        st1[t2] = __builtin_amdgcn_mfma_f32_16x16x32_bf16(k0, qf1[0], st1[t2], 0, 0, 0);
        st1[t2] = __builtin_amdgcn_mfma_f32_16x16x32_bf16(k1, qf1[1], st1[t2], 0, 0, 0);
        if (act0) {
          st0[t2] = __builtin_amdgcn_mfma_f32_16x16x32_bf16(k0, qf0[0], st0[t2], 0, 0, 0);
          st0[t2] = __builtin_amdgcn_mfma_f32_16x16x32_bf16(k1, qf0[1], st0[t2], 0, 0, 0);
        }
      }
      // ---- V fragments (A-operand: rows = hd, k = key offset)
      bf16x8 vf[4];
#pragma unroll
      for (int mt = 0; mt < 4; ++mt)
        vf[mt] = *(const bf16x8*)(Vs + (mt * 16 + lq) * 32 + quad * 8);

      // ================= qt1 softmax (inline, round-3 math) =================
      bf16x8 pf1;
      {
        const int qv = q1b + lq;
        float mx = -3e38f;
#pragma unroll
        for (int t2 = 0; t2 < 2; ++t2)
#pragma unroll
          for (int r = 0; r < 4; ++r) {
            const int key = kb + 8 * quad + 4 * t2 + r;
            const float v = (key <= qv) ? st1[t2][r] : -3e38f;
            st1[t2][r] = v;
            mx = fmaxf(mx, v);
          }
        mx = fmaxf(mx, __shfl_xor(mx, 16));
        mx = fmaxf(mx, __shfl_xor(mx, 32));
        const float mn = fmaxf(m1v, mx);
        const float al = __builtin_amdgcn_exp2f((m1v - mn) * Cc);
        m1v = mn;
        float rs = 0.0f;
#pragma unroll
        for (int t2 = 0; t2 < 2; ++t2)
#pragma unroll
          for (int r = 0; r < 4; ++r) {
            const float p = __builtin_amdgcn_exp2f((st1[t2][r] - mn) * Cc);
            rs += p;
            pf1[t2 * 4 + r] = f2bf(p);
          }
        rs += __shfl_xor(rs, 16);
        rs += __shfl_xor(rs, 32);
        l1v = l1v * al + rs;
#pragma unroll
        for (int mt = 0; mt < 4; ++mt)
#pragma unroll
          for (int r = 0; r < 4; ++r)
            o1[mt][r] *= al;
      }
      // ================= qt0 softmax (inline, round-3 math) =================
      bf16x8 pf0;
      if (act0) {
        const int qv = q0b + lq;
        float mx = -3e38f;
#pragma unroll
        for (int t2 = 0; t2 < 2; ++t2)
#pragma unroll
          for (int r = 0; r < 4; ++r) {
            const int key = kb + 8 * quad + 4 * t2 + r;
            const float v = (key <= qv) ? st0[t2][r] : -3e38f;
            st0[t2][r] = v;
            mx = fmaxf(mx, v);
          }
        mx = fmaxf(mx, __shfl_xor(mx, 16));
        mx = fmaxf(mx, __shfl_xor(mx, 32));
        const float mn = fmaxf(m0v, mx);
        const float al = __builtin_amdgcn_exp2f((m0v - mn) * Cc);
        m0v = mn;
        float rs = 0.0f;
#pragma unroll
        for (int t2 = 0; t2 < 2; ++t2)
#pragma unroll
          for (int r = 0; r < 4; ++r) {
            const float p = __builtin_amdgcn_exp2f((st0[t2][r] - mn) * Cc);
            rs += p;
            pf0[t2 * 4 + r] = f2bf(p);
          }
        rs += __shfl_xor(rs, 16);
        rs += __shfl_xor(rs, 32);
        l0v = l0v * al + rs;
#pragma unroll
        for (int mt = 0; mt < 4; ++mt)
#pragma unroll
          for (int r = 0; r < 4; ++r)
            o0[mt][r] *= al;
      }
      // ---- O^T += V^T . P^T
#pragma unroll
      for (int mt = 0; mt < 4; ++mt) {
        o1[mt] = __builtin_amdgcn_mfma_f32_16x16x32_bf16(vf[mt], pf1, o1[mt], 0, 0, 0);
        if (act0)
          o0[mt] = __builtin_amdgcn_mfma_f32_16x16x32_bf16(vf[mt], pf0, o0[mt], 0, 0, 0);
      }
    }
    __syncthreads();
  }

  // ---- epilogue: normalize, store (l already full per lane)
  {
    const float inv = 1.0f / l1v;
    const int q = q1b + lq;
#pragma unroll
    for (int mt = 0; mt < 4; ++mt) {
      short4 v;
      v.x = f2bf(o1[mt][0] * inv);
      v.y = f2bf(o1[mt][1] * inv);
      v.z = f2bf(o1[mt][2] * inv);
      v.w = f2bf(o1[mt][3] * inv);
      *(short4*)(AOb + ((size_t)(b * SEQ + q)) * DM + h * HD + mt * 16 + quad * 4) = v;
    }
  }
  {
    const float inv = 1.0f / l0v;
    const int q = q0b + lq;
#pragma unroll
    for (int mt = 0; mt < 4; ++mt) {
      short4 v;
      v.x = f2bf(o0[mt][0] * inv);
      v.y = f2bf(o0[mt][1] * inv);
      v.z = f2bf(o0[mt][2] * inv);
      v.w = f2bf(o0[mt][3] * inv);
      *(short4*)(AOb + ((size_t)(b * SEQ + q)) * DM + h * HD + mt * 16 + quad * 4) = v;
    }
  }
}

// ----------------------------------------------------------- output projection
__global__ __launch_bounds__(256) void out_gemm(
    const short* __restrict__ AOb, const short* __restrict__ Wob, float* __restrict__ C)
{
  __shared__ __align__(16) short As[4096], Bs[4096];
  const int m0 = blockIdx.y * 128, n0 = blockIdx.x * 128;
  f32x4 acc[4][4] = {};
  gemm_lds_core(AOb, Wob, As, Bs, m0, n0, acc);

  const int t = threadIdx.x;
  const int lane = t & 63, w = t >> 6;
  const int quad = lane >> 4, lq = lane & 15;
  const int mwb = m0 + (w & 1) * 64, nwb = n0 + (w >> 1) * 64;
#pragma unroll
  for (int mt = 0; mt < 4; ++mt)
#pragma unroll
    for (int nt = 0; nt < 4; ++nt) {
      const int n = nwb + nt * 16 + lq;
      const int mbase = mwb + mt * 16 + quad * 4;
#pragma unroll
      for (int r = 0; r < 4; ++r)
        C[(size_t)(mbase + r) * DM + n] = acc[mt][nt][r];
    }
}

// ------------------------------------------------------------------- launcher
extern "C" void kernel_launch(void* const* d_in, const int* in_sizes, int n_in,
                              void* d_out, int out_size, void* d_ws, size_t ws_size,
                              hipStream_t stream) {
  const float* x  = (const float*)d_in[0];
  const float* Wq = (const float*)d_in[1];
  const float* Wk = (const float*)d_in[2];
  const float* Wv = (const float*)d_in[3];
  const float* Wo = (const float*)d_in[4];
  float* out = (float*)d_out;

  short* xb  = (short*)d_ws;                       // 8192*768
  short* Wqb = xb  + (size_t)MTOT * DM;
  short* Wkb = Wqb + DM * DM;
  short* Wvb = Wkb + DM * DM;
  short* Wob = Wvb + DM * DM;
  short* Qb  = Wob + DM * DM;                      // (b,h,s,d)
  short* Kb  = Qb  + (size_t)MTOT * DM;            // (b,h,s,d)
  short* VTb = Kb  + (size_t)MTOT * DM;            // (b,h,d,s)
  short* AOb = xb;                                 // alias: xb dead after qkv_gemm

  const int TOT4 = (MTOT * DM + 4 * DM * DM) / 4;
  cvt5_kernel<<<(TOT4 + 255) / 256, 256, 0, stream>>>(x, Wq, Wk, Wv, Wo, xb);

  qkv_gemm<<<dim3(3 * DM / 128, MTOT / 128), 256, 0, stream>>>(xb, Wqb, Qb, Kb, VTb);
  attn_kernel<<<dim3(768), 256, 0, stream>>>(Qb, Kb, VTb, AOb);
  out_gemm<<<dim3(DM / 128, MTOT / 128), 256, 0, stream>>>(AOb, Wob, out);
}

// Round 7
// 237.101 us; speedup vs baseline: 2.9436x; 1.0164x over previous
//
#include <hip/hip_runtime.h>
#include <hip/hip_bf16.h>

// Problem constants
#define SEQ   2048
#define BATCH 4
#define DM    768
#define NH    12
#define HD    64
#define MTOT  (BATCH*SEQ)   // 8192

typedef short bf16x8 __attribute__((ext_vector_type(8)));   // 8 bf16 = 4 VGPRs
typedef float f32x4  __attribute__((ext_vector_type(4)));

static __device__ __forceinline__ short f2bf(float f) {
  union { __hip_bfloat16 h; short s; } u;
  u.h = __float2bfloat16(f);
  return u.s;
}

// async global->LDS, 16 B per lane (global_load_lds_dwordx4)
static __device__ __forceinline__ void async_cp16(const short* g, short* l) {
  __builtin_amdgcn_global_load_lds(
      (const __attribute__((address_space(1))) void*)g,
      (__attribute__((address_space(3))) void*)l, 16, 0, 0);
}

// ------------------------------------------- fused fp32 -> bf16 (x + 4 weights)
__global__ void cvt5_kernel(const float* __restrict__ x, const float* __restrict__ wq,
                            const float* __restrict__ wk, const float* __restrict__ wv,
                            const float* __restrict__ wo, short* __restrict__ dst) {
  const int NX4 = MTOT * DM / 4, NW4 = DM * DM / 4, TOT4 = NX4 + 4 * NW4;
  int i = blockIdx.x * blockDim.x + threadIdx.x;
  if (i >= TOT4) return;
  const float* src; int off;
  if (i < NX4) { src = x; off = i; }
  else {
    int j = i - NX4; int sel = j / NW4; off = j - sel * NW4;
    src = (sel == 0) ? wq : (sel == 1) ? wk : (sel == 2) ? wv : wo;
  }
  float4 v = reinterpret_cast<const float4*>(src)[off];
  short4 o;
  o.x = f2bf(v.x); o.y = f2bf(v.y); o.z = f2bf(v.z); o.w = f2bf(v.w);
  reinterpret_cast<short4*>(dst)[i] = o;
}

// ---------------------------------------------- m97-style 128x128 LDS-staged GEMM core
static __device__ __forceinline__ void gemm_lds_core(
    const short* __restrict__ A, const short* __restrict__ W,
    short* As, short* Bs, int m0, int n0, f32x4 acc[4][4])
{
  const int t = threadIdx.x;
  const int lane = t & 63, w = t >> 6;
  const int quad = lane >> 4, lq = lane & 15;
  const int mw = (w & 1) * 64, nw = (w >> 1) * 64;
  const int r0 = t >> 2, c0 = (t & 3) * 8;
  const short* ga0 = A + (size_t)(m0 + r0) * DM + c0;
  const short* ga1 = A + (size_t)(m0 + 64 + r0) * DM + c0;
  const short* gb0 = W + (size_t)(n0 + r0) * DM + c0;
  const short* gb1 = W + (size_t)(n0 + 64 + r0) * DM + c0;
  short* la0 = As + t * 8;
  short* la1 = As + 2048 + t * 8;
  short* lb0 = Bs + t * 8;
  short* lb1 = Bs + 2048 + t * 8;

  for (int k0 = 0; k0 < DM; k0 += 32) {
    async_cp16(ga0 + k0, la0);
    async_cp16(ga1 + k0, la1);
    async_cp16(gb0 + k0, lb0);
    async_cp16(gb1 + k0, lb1);
    __syncthreads();
    bf16x8 af[4], bf[4];
#pragma unroll
    for (int i = 0; i < 4; ++i) {
      af[i] = *(const bf16x8*)(As + (mw + i * 16 + lq) * 32 + quad * 8);
      bf[i] = *(const bf16x8*)(Bs + (nw + i * 16 + lq) * 32 + quad * 8);
    }
#pragma unroll
    for (int mt = 0; mt < 4; ++mt)
#pragma unroll
      for (int nt = 0; nt < 4; ++nt)
        acc[mt][nt] = __builtin_amdgcn_mfma_f32_16x16x32_bf16(af[mt], bf[nt], acc[mt][nt], 0, 0, 0);
    __syncthreads();
  }
}

// --------------------------------------------------------------- fused QKV projection
__global__ __launch_bounds__(256) void qkv_gemm(
    const short* __restrict__ xb, const short* __restrict__ Wall,
    short* __restrict__ Qb, short* __restrict__ Kb, short* __restrict__ VTb)
{
  __shared__ __align__(16) short As[4096], Bs[4096];
  const int m0 = blockIdx.y * 128, n0 = blockIdx.x * 128;
  f32x4 acc[4][4] = {};
  gemm_lds_core(xb, Wall, As, Bs, m0, n0, acc);

  const int t = threadIdx.x;
  const int lane = t & 63, w = t >> 6;
  const int quad = lane >> 4, lq = lane & 15;
  const int mwb = m0 + (w & 1) * 64, nwb = n0 + (w >> 1) * 64;
#pragma unroll
  for (int mt = 0; mt < 4; ++mt)
#pragma unroll
    for (int nt = 0; nt < 4; ++nt) {
      const int n = nwb + nt * 16 + lq;
      const int z = n / DM, nn = n % DM;
      const int h = nn >> 6, d = nn & 63;
      const int mbase = mwb + mt * 16 + quad * 4;
      const int b = mbase >> 11, s0 = mbase & 2047;
      if (z == 2) {
        short4 v;
        v.x = f2bf(acc[mt][nt][0]); v.y = f2bf(acc[mt][nt][1]);
        v.z = f2bf(acc[mt][nt][2]); v.w = f2bf(acc[mt][nt][3]);
        *(short4*)(VTb + ((size_t)(b * NH + h) * HD + d) * SEQ + s0) = v;
      } else {
        short* dst = (z == 0) ? Qb : Kb;
#pragma unroll
        for (int r = 0; r < 4; ++r)
          dst[((size_t)(b * NH + h) * SEQ + s0 + r) * HD + d] = f2bf(acc[mt][nt][r]);
      }
    }
}

// ------------------------------------------------------------ flash attention
// Round-5 softmax semantics EXACTLY (unconditional mask, per-step reduced
// rowsum, l = l*al + rs). Two exact-semantics deltas vs round 5:
//   (1) K-tile chunk-XOR swizzle to kill the measured 9.5M bank-conflict
//       cycles: LDS[row][slot] holds global chunk slot^swz(row),
//       swz(r) = (r&3)|(((r>>3)&1)<<2); reader fetches slot chunk^swz(row).
//   (2) wave-uniform skip of the o/l rescale when al==1.0f for all lanes
//       (exp2(0)=1 exactly; multiply-by-1 is an exact FP identity).
__global__ __launch_bounds__(256) void attn_kernel(
    const short* __restrict__ Qb, const short* __restrict__ Kb,
    const short* __restrict__ VTb, short* __restrict__ AOb)
{
  __shared__ __align__(16) short Ks[32 * 64];   // [keyoff][hd], chunk-swizzled
  __shared__ __align__(16) short Vs[64 * 32];   // [hd][keyoff]
  const int bp = blockIdx.x;
  const int bh = bp % 48;
  const int g  = bp / 48;              // 0..15
  const int tid = threadIdx.x;
  const int w = tid >> 6, lane = tid & 63;
  const int quad = lane >> 4, lq = lane & 15;
  const int tp = 4 * g + w;            // pair id 0..63
  const int b = bh / NH, h = bh % NH;
  const int q0b = 16 * tp;             // qt0 query base
  const int q1b = 2032 - 16 * tp;      // qt1 query base
  const int E0 = q0b + 16;             // qt0 key range end
  const int E1 = q1b + 16;             // qt1 key range end
  const int Eblk = 2048 - 64 * g;      // block-uniform loop bound (= E1 of w=0)

  const short* Qh = Qb  + (size_t)bh * SEQ * HD;
  const short* Kh = Kb  + (size_t)bh * SEQ * HD;
  const short* Vh = VTb + (size_t)bh * HD * SEQ;

  // Q fragments (B-operand): lane holds Q[qb+lq][hh*32+quad*8+j]
  bf16x8 qf0[2], qf1[2];
#pragma unroll
  for (int hh = 0; hh < 2; ++hh) {
    qf0[hh] = *(const bf16x8*)(Qh + (size_t)(q0b + lq) * HD + hh * 32 + quad * 8);
    qf1[hh] = *(const bf16x8*)(Qh + (size_t)(q1b + lq) * HD + hh * 32 + quad * 8);
  }

  f32x4 o0[4] = {}, o1[4] = {};        // O^T[hd=mt*16+quad*4+r][q=qb+lq]
  float m0v = -3e38f, m1v = -3e38f;
  float l0v = 0.0f, l1v = 0.0f;        // full per-lane l (round-5 semantics)
  const float Cc = 0.18033688011112042f;  // log2(e)/sqrt(64)

  // ---- K staging, source-swizzled: LDS slot s of row r holds global chunk
  // s^swz(r); LDS dest stays linear (tid*16B, per global_load_lds rule).
  const int srow = tid >> 3, sslot = tid & 7;
  const int sswz = (srow & 3) | (((srow >> 3) & 1) << 2);
  const short* gK = Kh + (size_t)srow * HD + (sslot ^ sswz) * 8;
  const short* gV = Vh + (size_t)(tid >> 2) * SEQ + (tid & 3) * 8;
  short* lK = Ks + tid * 8;
  short* lV = Vs + tid * 8;

  // reader-side swizzle: rows 8*(lq>>2)+4*t2+(lq&3) all have
  // swz(row) = (lq&3)|(((lq>>2)&1)<<2)
  const int rswz = (lq & 3) | (((lq >> 2) & 1) << 2);

  for (int kb = 0; kb < Eblk; kb += 32) {
    async_cp16(gK + (size_t)kb * HD, lK);
    async_cp16(gV + kb, lV);
    __syncthreads();
    if (kb < E1) {
      const bool act0 = kb < E0;
      // ---- S^T = K.Q^T (K rows permuted so P exits in PV B-operand layout)
      f32x4 st0[2] = {}, st1[2] = {};
#pragma unroll
      for (int t2 = 0; t2 < 2; ++t2) {
        const int row = 8 * (lq >> 2) + 4 * t2 + (lq & 3);
        const int sl0 = quad ^ rswz;
        bf16x8 k0 = *(const bf16x8*)(Ks + row * 64 + sl0 * 8);
        bf16x8 k1 = *(const bf16x8*)(Ks + row * 64 + (sl0 ^ 4) * 8);
        st1[t2] = __builtin_amdgcn_mfma_f32_16x16x32_bf16(k0, qf1[0], st1[t2], 0, 0, 0);
        st1[t2] = __builtin_amdgcn_mfma_f32_16x16x32_bf16(k1, qf1[1], st1[t2], 0, 0, 0);
        if (act0) {
          st0[t2] = __builtin_amdgcn_mfma_f32_16x16x32_bf16(k0, qf0[0], st0[t2], 0, 0, 0);
          st0[t2] = __builtin_amdgcn_mfma_f32_16x16x32_bf16(k1, qf0[1], st0[t2], 0, 0, 0);
        }
      }
      // ---- V fragments (A-operand: rows = hd, k = key offset; conflict-free)
      bf16x8 vf[4];
#pragma unroll
      for (int mt = 0; mt < 4; ++mt)
        vf[mt] = *(const bf16x8*)(Vs + (mt * 16 + lq) * 32 + quad * 8);

      // ================= qt1 softmax (inline, round-3/5 math) =================
      bf16x8 pf1;
      {
        const int qv = q1b + lq;
        float mx = -3e38f;
#pragma unroll
        for (int t2 = 0; t2 < 2; ++t2)
#pragma unroll
          for (int r = 0; r < 4; ++r) {
            const int key = kb + 8 * quad + 4 * t2 + r;
            const float v = (key <= qv) ? st1[t2][r] : -3e38f;
            st1[t2][r] = v;
            mx = fmaxf(mx, v);
          }
        mx = fmaxf(mx, __shfl_xor(mx, 16));
        mx = fmaxf(mx, __shfl_xor(mx, 32));
        const float mn = fmaxf(m1v, mx);
        const float al = __builtin_amdgcn_exp2f((m1v - mn) * Cc);
        m1v = mn;
        float rs = 0.0f;
#pragma unroll
        for (int t2 = 0; t2 < 2; ++t2)
#pragma unroll
          for (int r = 0; r < 4; ++r) {
            const float p = __builtin_amdgcn_exp2f((st1[t2][r] - mn) * Cc);
            rs += p;
            pf1[t2 * 4 + r] = f2bf(p);
          }
        rs += __shfl_xor(rs, 16);
        rs += __shfl_xor(rs, 32);
        if (!__all(al == 1.0f)) {      // exact identity skip (mul by 1.0)
          l1v *= al;
#pragma unroll
          for (int mt = 0; mt < 4; ++mt)
#pragma unroll
            for (int r = 0; r < 4; ++r)
              o1[mt][r] *= al;
        }
        l1v += rs;
      }
      // ================= qt0 softmax (inline, round-3/5 math) =================
      bf16x8 pf0;
      if (act0) {
        const int qv = q0b + lq;
        float mx = -3e38f;
#pragma unroll
        for (int t2 = 0; t2 < 2; ++t2)
#pragma unroll
          for (int r = 0; r < 4; ++r) {
            const int key = kb + 8 * quad + 4 * t2 + r;
            const float v = (key <= qv) ? st0[t2][r] : -3e38f;
            st0[t2][r] = v;
            mx = fmaxf(mx, v);
          }
        mx = fmaxf(mx, __shfl_xor(mx, 16));
        mx = fmaxf(mx, __shfl_xor(mx, 32));
        const float mn = fmaxf(m0v, mx);
        const float al = __builtin_amdgcn_exp2f((m0v - mn) * Cc);
        m0v = mn;
        float rs = 0.0f;
#pragma unroll
        for (int t2 = 0; t2 < 2; ++t2)
#pragma unroll
          for (int r = 0; r < 4; ++r) {
            const float p = __builtin_amdgcn_exp2f((st0[t2][r] - mn) * Cc);
            rs += p;
            pf0[t2 * 4 + r] = f2bf(p);
          }
        rs += __shfl_xor(rs, 16);
        rs += __shfl_xor(rs, 32);
        if (!__all(al == 1.0f)) {      // exact identity skip (mul by 1.0)
          l0v *= al;
#pragma unroll
          for (int mt = 0; mt < 4; ++mt)
#pragma unroll
            for (int r = 0; r < 4; ++r)
              o0[mt][r] *= al;
        }
        l0v += rs;
      }
      // ---- O^T += V^T . P^T
#pragma unroll
      for (int mt = 0; mt < 4; ++mt) {
        o1[mt] = __builtin_amdgcn_mfma_f32_16x16x32_bf16(vf[mt], pf1, o1[mt], 0, 0, 0);
        if (act0)
          o0[mt] = __builtin_amdgcn_mfma_f32_16x16x32_bf16(vf[mt], pf0, o0[mt], 0, 0, 0);
      }
    }
    __syncthreads();
  }

  // ---- epilogue: normalize, store (l already full per lane)
  {
    const float inv = 1.0f / l1v;
    const int q = q1b + lq;
#pragma unroll
    for (int mt = 0; mt < 4; ++mt) {
      short4 v;
      v.x = f2bf(o1[mt][0] * inv);
      v.y = f2bf(o1[mt][1] * inv);
      v.z = f2bf(o1[mt][2] * inv);
      v.w = f2bf(o1[mt][3] * inv);
      *(short4*)(AOb + ((size_t)(b * SEQ + q)) * DM + h * HD + mt * 16 + quad * 4) = v;
    }
  }
  {
    const float inv = 1.0f / l0v;
    const int q = q0b + lq;
#pragma unroll
    for (int mt = 0; mt < 4; ++mt) {
      short4 v;
      v.x = f2bf(o0[mt][0] * inv);
      v.y = f2bf(o0[mt][1] * inv);
      v.z = f2bf(o0[mt][2] * inv);
      v.w = f2bf(o0[mt][3] * inv);
      *(short4*)(AOb + ((size_t)(b * SEQ + q)) * DM + h * HD + mt * 16 + quad * 4) = v;
    }
  }
}

// ----------------------------------------------------------- output projection
__global__ __launch_bounds__(256) void out_gemm(
    const short* __restrict__ AOb, const short* __restrict__ Wob, float* __restrict__ C)
{
  __shared__ __align__(16) short As[4096], Bs[4096];
  const int m0 = blockIdx.y * 128, n0 = blockIdx.x * 128;
  f32x4 acc[4][4] = {};
  gemm_lds_core(AOb, Wob, As, Bs, m0, n0, acc);

  const int t = threadIdx.x;
  const int lane = t & 63, w = t >> 6;
  const int quad = lane >> 4, lq = lane & 15;
  const int mwb = m0 + (w & 1) * 64, nwb = n0 + (w >> 1) * 64;
#pragma unroll
  for (int mt = 0; mt < 4; ++mt)
#pragma unroll
    for (int nt = 0; nt < 4; ++nt) {
      const int n = nwb + nt * 16 + lq;
      const int mbase = mwb + mt * 16 + quad * 4;
#pragma unroll
      for (int r = 0; r < 4; ++r)
        C[(size_t)(mbase + r) * DM + n] = acc[mt][nt][r];
    }
}

// ------------------------------------------------------------------- launcher
extern "C" void kernel_launch(void* const* d_in, const int* in_sizes, int n_in,
                              void* d_out, int out_size, void* d_ws, size_t ws_size,
                              hipStream_t stream) {
  const float* x  = (const float*)d_in[0];
  const float* Wq = (const float*)d_in[1];
  const float* Wk = (const float*)d_in[2];
  const float* Wv = (const float*)d_in[3];
  const float* Wo = (const float*)d_in[4];
  float* out = (float*)d_out;

  short* xb  = (short*)d_ws;                       // 8192*768
  short* Wqb = xb  + (size_t)MTOT * DM;
  short* Wkb = Wqb + DM * DM;
  short* Wvb = Wkb + DM * DM;
  short* Wob = Wvb + DM * DM;
  short* Qb  = Wob + DM * DM;                      // (b,h,s,d)
  short* Kb  = Qb  + (size_t)MTOT * DM;            // (b,h,s,d)
  short* VTb = Kb  + (size_t)MTOT * DM;            // (b,h,d,s)
  short* AOb = xb;                                 // alias: xb dead after qkv_gemm

  const int TOT4 = (MTOT * DM + 4 * DM * DM) / 4;
  cvt5_kernel<<<(TOT4 + 255) / 256, 256, 0, stream>>>(x, Wq, Wk, Wv, Wo, xb);

  qkv_gemm<<<dim3(3 * DM / 128, MTOT / 128), 256, 0, stream>>>(xb, Wqb, Qb, Kb, VTb);
  attn_kernel<<<dim3(768), 256, 0, stream>>>(Qb, Kb, VTb, AOb);
  out_gemm<<<dim3(DM / 128, MTOT / 128), 256, 0, stream>>>(AOb, Wob, out);
}